// Round 1
// 601.776 us; speedup vs baseline: 1.0204x; 1.0204x over previous
//
#include <hip/hip_runtime.h>
#include <hip/hip_bf16.h>
#include <math.h>

#define N_GENE 50000
#define N_DIS  25000
#define F_GENE 512
#define F_DIS  256
#define E_EDGES 150000
#define BN_EPS 1e-5f

typedef unsigned short u16;
typedef unsigned int u32;
typedef short s16x8 __attribute__((ext_vector_type(8)));
typedef float f32x4 __attribute__((ext_vector_type(4)));

__device__ __forceinline__ u16 f2bf(float f) {
    union { float f; unsigned u; } c; c.f = f;
    unsigned u = c.u;
    unsigned rounding = 0x7FFFu + ((u >> 16) & 1u);
    return (u16)((u + rounding) >> 16);
}
__device__ __forceinline__ void load_bf16x8(const u16* p, float* f) {
    uint4 q = *reinterpret_cast<const uint4*>(p);
    unsigned w0 = q.x, w1 = q.y, w2 = q.z, w3 = q.w;
    f[0] = __uint_as_float(w0 << 16); f[1] = __uint_as_float(w0 & 0xffff0000u);
    f[2] = __uint_as_float(w1 << 16); f[3] = __uint_as_float(w1 & 0xffff0000u);
    f[4] = __uint_as_float(w2 << 16); f[5] = __uint_as_float(w2 & 0xffff0000u);
    f[6] = __uint_as_float(w3 << 16); f[7] = __uint_as_float(w3 & 0xffff0000u);
}

// async global->LDS, 16B per lane; LDS dest is wave-uniform base + lane*16
__device__ __forceinline__ void gload_lds16(const u16* g, u16* l) {
    __builtin_amdgcn_global_load_lds(
        (const __attribute__((address_space(1))) u32*)g,
        (__attribute__((address_space(3))) u32*)l, 16, 0, 0);
}

// ---------------- zero fill ----------------
__global__ void zero_kernel(int* p, int n) {
    int i = blockIdx.x * 256 + threadIdx.x;
    if (i < n) p[i] = 0;
}

// ---- B pack: W f32 [K][N] -> fragment-major bf16 Bp[nt][KC][64][8]
__global__ void pack_b(const float* __restrict__ W, u16* __restrict__ Bp, int K, int N) {
    int i = blockIdx.x * 256 + threadIdx.x;
    int K8 = K >> 3;
    if (i >= N * K8) return;
    int n = i / K8, ko = i - n * K8;
    int k0 = ko * 8;
    int nt = n >> 4, mr = n & 15, kc = k0 >> 5, quad = (k0 >> 3) & 3;
    u16 tmp[8];
#pragma unroll
    for (int j = 0; j < 8; j++) tmp[j] = f2bf(W[(size_t)(k0 + j) * N + n]);
    *reinterpret_cast<uint4*>(&Bp[((size_t)(nt * (K >> 5) + kc) * 64 + quad * 16 + mr) * 8]) =
        *reinterpret_cast<const uint4*>(tmp);
}

// ---- GEMM, software-pipelined: double-buffered LDS B (global_load_lds) +
// ---- one-chunk-ahead A register prefetch, counted vmcnt fences (never 0 mid-loop).
// Block: 4 waves x 16 rows, 128-col slab. Chunk = CK=2 kc-frags (16KB LDS per buf).
template <int K, bool A_FRAG, bool RELU_BIAS, bool OUT_BF16>
__global__ __launch_bounds__(256) void gemm_lds(const void* __restrict__ Ap,
                                                const u16* __restrict__ Bp,
                                                const float* __restrict__ bias,
                                                void* __restrict__ outp, int M, int NFULL) {
    constexpr int KC = K / 32;          // 16 / 8 / 4
    constexpr int CK = 2;               // kc per chunk
    constexpr int NCH = KC / CK;        // 8 / 4 / 2  (always even)
    __shared__ u16 Bs[2][8 * CK * 64 * 8];   // 2 x 16KB
    const int wave = threadIdx.x >> 6;
    const int lane = threadIdx.x & 63;
    const int mrow = lane & 15;
    const int quad = lane >> 4;
    const int m0 = (blockIdx.x * 4 + wave) * 16;
    const int n0 = blockIdx.y * 128;
    const int arow = (m0 + mrow < M) ? m0 + mrow : M - 1;
    const int rt = (m0 >> 4) < ((M + 15) >> 4) ? (m0 >> 4) : ((M + 15) >> 4) - 1;
    const u16* bslab = Bp + (size_t)(n0 >> 4) * KC * 512;  // 512 u16 per frag

    f32x4 acc[8];
#pragma unroll
    for (int t = 0; t < 8; t++) acc[t] = (f32x4){0.f, 0.f, 0.f, 0.f};

    struct ARegs { float4 f[2 * CK]; s16x8 s[CK]; };
    ARegs A0, A1;

    // stage chunk c into Bs[b]: 8nt*CK frags, 2*CK per wave, async 16B/lane
    auto stageB = [&](int c, int b) {
#pragma unroll
        for (int q = 0; q < 2 * CK; q++) {
            int fi = wave * 2 * CK + q;
            int t = fi / CK, kcp = fi % CK;
            const u16* g = bslab + ((size_t)(t * KC + c * CK + kcp) * 64 + lane) * 8;
            gload_lds16(g, &Bs[b][(size_t)fi * 512]);
        }
    };
    auto loadA = [&](int c, ARegs& A) {
        if constexpr (A_FRAG) {
#pragma unroll
            for (int kcp = 0; kcp < CK; kcp++)
                A.s[kcp] = *reinterpret_cast<const s16x8*>(
                    (const u16*)Ap + ((size_t)(rt * KC + c * CK + kcp) * 64 + lane) * 8);
        } else {
#pragma unroll
            for (int kcp = 0; kcp < CK; kcp++) {
                const float* ap = (const float*)Ap + (size_t)arow * K + (c * CK + kcp) * 32 + quad * 8;
                A.f[2 * kcp]     = *reinterpret_cast<const float4*>(ap);
                A.f[2 * kcp + 1] = *reinterpret_cast<const float4*>(ap + 4);
            }
        }
    };
    auto compute = [&](const u16* Bsb, const ARegs& A) {
#pragma unroll
        for (int kcp = 0; kcp < CK; kcp++) {
            s16x8 af;
            if constexpr (A_FRAG) {
                af = A.s[kcp];
            } else {
                const float4 lo = A.f[2 * kcp], hi = A.f[2 * kcp + 1];
                af[0] = (short)f2bf(lo.x); af[1] = (short)f2bf(lo.y);
                af[2] = (short)f2bf(lo.z); af[3] = (short)f2bf(lo.w);
                af[4] = (short)f2bf(hi.x); af[5] = (short)f2bf(hi.y);
                af[6] = (short)f2bf(hi.z); af[7] = (short)f2bf(hi.w);
            }
#pragma unroll
            for (int t = 0; t < 8; t++) {
                const s16x8 bfr = *reinterpret_cast<const s16x8*>(
                    &Bsb[((size_t)(t * CK + kcp) * 64 + lane) * 8]);
                acc[t] = __builtin_amdgcn_mfma_f32_16x16x32_bf16(af, bfr, acc[t], 0, 0, 0);
            }
        }
    };

    // per-wave outstanding after issuing next chunk: stage(2*CK=4) + loadA(4 f32 / 2 frag)
#define FENCE_N() do { if constexpr (A_FRAG) asm volatile("s_waitcnt vmcnt(6)" ::: "memory"); \
                       else                  asm volatile("s_waitcnt vmcnt(8)" ::: "memory"); } while (0)
#define FENCE_0() asm volatile("s_waitcnt vmcnt(0)" ::: "memory")
#define LGKM0()   asm volatile("s_waitcnt lgkmcnt(0)" ::: "memory")
#define BAR()     asm volatile("s_barrier" ::: "memory")

    stageB(0, 0);
    loadA(0, A0);
    for (int cc = 0; cc < NCH / 2; ++cc) {
        // phase A: compute chunk 2cc (buf0/A0), prefetch chunk 2cc+1 (buf1/A1)
        stageB(2 * cc + 1, 1);
        loadA(2 * cc + 1, A1);
        FENCE_N();              // chunk 2cc's B-in-LDS + A0 complete
        BAR();
        compute(&Bs[0][0], A0);
        LGKM0();                // ds_reads of buf0 drained before others overwrite it
        BAR();
        // phase B: compute chunk 2cc+1 (buf1/A1), prefetch chunk 2cc+2 (buf0/A0)
        if (cc + 1 < NCH / 2) {
            stageB(2 * cc + 2, 0);
            loadA(2 * cc + 2, A0);
            FENCE_N();
        } else {
            FENCE_0();
        }
        BAR();
        compute(&Bs[1][0], A1);
        LGKM0();
        BAR();
    }
#undef FENCE_N
#undef FENCE_0
#undef LGKM0
#undef BAR

#pragma unroll
    for (int t = 0; t < 8; t++) {
        int col = n0 + t * 16 + mrow;
#pragma unroll
        for (int r = 0; r < 4; r++) {
            int orow = m0 + quad * 4 + r;
            if (orow < M) {
                float v = acc[t][r];
                if (RELU_BIAS) v = fmaxf(v + bias[col], 0.f);
                if (OUT_BF16)
                    ((u16*)outp)[(size_t)orow * NFULL + col] = f2bf(v);
                else
                    ((float*)outp)[(size_t)orow * NFULL + col] = v;
            }
        }
    }
}

// ---- batchnorm stats ----
__global__ void col_stats(const float* __restrict__ X, int M, float* __restrict__ stats) {
    int col = threadIdx.x;  // 128
    float s = 0.f, s2 = 0.f;
    for (int r = blockIdx.x; r < M; r += gridDim.x) {
        float v = X[(size_t)r * 128 + col];
        s += v; s2 += v * v;
    }
    atomicAdd(&stats[col], s);
    atomicAdd(&stats[128 + col], s2);
}

// bn in place; optional bf16 FRAGMENT-MAJOR mirror (A for rel GEMM, K=128 -> KC=4)
__global__ void bn_apply(float* __restrict__ X, const float* __restrict__ stats,
                         const float* __restrict__ gamma, const float* __restrict__ beta,
                         u16* __restrict__ mirror, int M) {
    int i = blockIdx.x * 256 + threadIdx.x;   // M*16 threads, 8 cols each
    if (i >= M * 16) return;
    int row = i >> 4, cg = i & 15;
    float inv_m = 1.0f / (float)M;
    float4 lo = *reinterpret_cast<const float4*>(&X[(size_t)row * 128 + cg * 8]);
    float4 hi = *reinterpret_cast<const float4*>(&X[(size_t)row * 128 + cg * 8 + 4]);
    float v[8] = {lo.x, lo.y, lo.z, lo.w, hi.x, hi.y, hi.z, hi.w};
    u16 mb[8];
#pragma unroll
    for (int e = 0; e < 8; e++) {
        int col = cg * 8 + e;
        float mu = stats[col] * inv_m;
        float var = stats[128 + col] * inv_m - mu * mu;
        v[e] = gamma[col] * (v[e] - mu) * rsqrtf(var + BN_EPS) + beta[col];
        mb[e] = f2bf(v[e]);
    }
    *reinterpret_cast<float4*>(&X[(size_t)row * 128 + cg * 8]) = (float4){v[0], v[1], v[2], v[3]};
    *reinterpret_cast<float4*>(&X[(size_t)row * 128 + cg * 8 + 4]) = (float4){v[4], v[5], v[6], v[7]};
    if (mirror) {
        int kc = cg >> 2, quad = cg & 3, ml = quad * 16 + (row & 15), rt = row >> 4;
        *reinterpret_cast<uint4*>(&mirror[((size_t)(rt * 4 + kc) * 64 + ml) * 8]) =
            *reinterpret_cast<const uint4*>(mb);
    }
}

// ---- weff[h*128+k] = sum_c Wd[k, h*128+c] * ad[h*128+c] ----
__global__ void weff_kernel(const float* __restrict__ Wd, const float* __restrict__ ad,
                            float* __restrict__ weff) {
    int t = blockIdx.x * 256 + threadIdx.x;
    if (t >= 512) return;
    int h = t >> 7, k = t & 127;
    float s = 0.f;
    for (int c = 0; c < 128; c++)
        s += Wd[k * 512 + h * 128 + c] * ad[h * 128 + c];
    weff[h * 128 + k] = s;
}

// ---- ld[n,h] = X[n,:] @ weff[h,:]  (one wave per node) ----
__global__ void ld_kernel(const float* __restrict__ X, const float* __restrict__ weff,
                          float* __restrict__ ld, int M) {
    int wid = (blockIdx.x * blockDim.x + threadIdx.x) >> 6;
    int lane = threadIdx.x & 63;
    if (wid >= M) return;
    float x0 = X[(size_t)wid * 128 + lane];
    float x1 = X[(size_t)wid * 128 + 64 + lane];
    #pragma unroll
    for (int h = 0; h < 4; h++) {
        float p = x0 * weff[h * 128 + lane] + x1 * weff[h * 128 + 64 + lane];
        p += __shfl_xor(p, 32, 64);
        p += __shfl_xor(p, 16, 64);
        p += __shfl_xor(p, 8, 64);
        p += __shfl_xor(p, 4, 64);
        p += __shfl_xor(p, 2, 64);
        p += __shfl_xor(p, 1, 64);
        if (lane == 0) ld[wid * 4 + h] = p;
    }
}

// ---- ls[n,h] = sum_c xs[n,h,c]*as[h,c] ----
__global__ void ls_kernel(const u16* __restrict__ xs, const float* __restrict__ as_,
                          float* __restrict__ ls, int M) {
    int wid = (blockIdx.x * blockDim.x + threadIdx.x) >> 6;
    int lane = threadIdx.x & 63;
    if (wid >= M) return;
    float xv[8];
    load_bf16x8(xs + (size_t)wid * 512 + lane * 8, xv);
    const float* ap = as_ + lane * 8;
    float s = 0.f;
    #pragma unroll
    for (int k = 0; k < 8; k++) s += xv[k] * ap[k];
    s += __shfl_xor(s, 1, 64);
    s += __shfl_xor(s, 2, 64);
    s += __shfl_xor(s, 4, 64);
    s += __shfl_xor(s, 8, 64);
    if ((lane & 15) == 0) ls[wid * 4 + (lane >> 4)] = s;
}

// ---------------- CSR build ----------------
__global__ void count_edges(const int* __restrict__ src, const int* __restrict__ dst,
                            int E, int n_loop, int* __restrict__ deg) {
    int e = blockIdx.x * 256 + threadIdx.x;
    if (e >= E + n_loop) return;
    int s, d;
    if (e < E) { s = src[e]; d = dst[e]; if (s == d) return; }
    else { s = e - E; d = s; }
    atomicAdd(&deg[d], 1);
}

__global__ void block_sum(const int* __restrict__ deg, int* __restrict__ bsum, int n) {
    __shared__ int sh[256];
    int i = blockIdx.x * 256 + threadIdx.x;
    sh[threadIdx.x] = (i < n) ? deg[i] : 0;
    __syncthreads();
    for (int s = 128; s > 0; s >>= 1) {
        if (threadIdx.x < s) sh[threadIdx.x] += sh[threadIdx.x + s];
        __syncthreads();
    }
    if (threadIdx.x == 0) bsum[blockIdx.x] = sh[0];
}

__global__ void scan_bsum(int* __restrict__ bsum, int nb, int* __restrict__ total_out) {
    __shared__ int sh[256];
    int tid = threadIdx.x;
    int v = (tid < nb) ? bsum[tid] : 0;
    sh[tid] = v;
    __syncthreads();
    for (int off = 1; off < 256; off <<= 1) {
        int t = (tid >= off) ? sh[tid - off] : 0;
        __syncthreads();
        sh[tid] += t;
        __syncthreads();
    }
    if (tid < nb) bsum[tid] = sh[tid] - v;   // exclusive
    if (tid == 255) *total_out = sh[255];
}

__global__ void scan_final(const int* __restrict__ deg, const int* __restrict__ bsum,
                           int* __restrict__ offs, int* __restrict__ cursor, int n) {
    __shared__ int sh[256];
    int i = blockIdx.x * 256 + threadIdx.x;
    int tid = threadIdx.x;
    int v = (i < n) ? deg[i] : 0;
    sh[tid] = v;
    __syncthreads();
    for (int off = 1; off < 256; off <<= 1) {
        int t = (tid >= off) ? sh[tid - off] : 0;
        __syncthreads();
        sh[tid] += t;
        __syncthreads();
    }
    int ex = bsum[blockIdx.x] + sh[tid] - v;
    if (i < n) { offs[i] = ex; cursor[i] = ex; }
}

__global__ void scatter_edges(const int* __restrict__ src, const int* __restrict__ dst,
                              int E, int n_loop, int* __restrict__ cursor,
                              int* __restrict__ esrc) {
    int e = blockIdx.x * 256 + threadIdx.x;
    if (e >= E + n_loop) return;
    int s, d;
    if (e < E) { s = src[e]; d = dst[e]; if (s == d) return; }
    else { s = e - E; d = s; }
    int pos = atomicAdd(&cursor[d], 1);
    esrc[pos] = s;
}

// ---- GAT aggregation: one wave per dst node; updates xdst_out in place ----
__global__ void gat_kernel(const int* __restrict__ offs, const int* __restrict__ esrc,
                           const float* __restrict__ ls, const float* __restrict__ ld,
                           const u16* __restrict__ xs, const float* __restrict__ bias,
                           float* __restrict__ xdst_out, u16* __restrict__ mirror, int n_dst) {
    int wid = (blockIdx.x * blockDim.x + threadIdx.x) >> 6;
    int lane = threadIdx.x & 63;
    if (wid >= n_dst) return;
    int h = lane >> 4;
    int beg = offs[wid], end = offs[wid + 1];
    float ldv = ld[wid * 4 + h];
    float m = -INFINITY;
    for (int j = beg; j < end; j++) {
        int s = esrc[j];
        float l = ls[s * 4 + h] + ldv;
        l = l > 0.f ? l : 0.2f * l;
        m = fmaxf(m, l);
    }
    float denom = 0.f;
    float acc[8] = {0.f, 0.f, 0.f, 0.f, 0.f, 0.f, 0.f, 0.f};
    for (int j = beg; j < end; j++) {
        int s = esrc[j];
        float l = ls[s * 4 + h] + ldv;
        l = l > 0.f ? l : 0.2f * l;
        float p = __expf(l - m);
        denom += p;
        float xv[8];
        load_bf16x8(xs + (size_t)s * 512 + lane * 8, xv);
        #pragma unroll
        for (int k = 0; k < 8; k++) acc[k] += p * xv[k];
    }
    float dinv = denom > 0.f ? 1.f / denom : 1.f;
    #pragma unroll
    for (int k = 0; k < 8; k++) {
        float v = acc[k] * dinv;
        v += __shfl_xor(v, 16, 64);
        v += __shfl_xor(v, 32, 64);
        acc[k] = v * 0.25f;
    }
    if (lane < 16) {
        int c0 = lane * 8;
        float vout[8];
        #pragma unroll
        for (int k = 0; k < 8; k++) {
            vout[k] = xdst_out[(size_t)wid * 128 + c0 + k] + acc[k] + bias[c0 + k];
            xdst_out[(size_t)wid * 128 + c0 + k] = vout[k];
        }
        if (mirror) {
            unsigned pk[4];
            #pragma unroll
            for (int kk = 0; kk < 4; kk++)
                pk[kk] = (unsigned)f2bf(vout[2 * kk]) | ((unsigned)f2bf(vout[2 * kk + 1]) << 16);
            int kc = lane >> 2, quad = lane & 3, ml = quad * 16 + (wid & 15), rt = wid >> 4;
            *reinterpret_cast<uint4*>(&mirror[((size_t)(rt * 4 + kc) * 64 + ml) * 8]) =
                *reinterpret_cast<const uint4*>(pk);
        }
    }
}

static inline int cdiv(int a, int b) { return (a + b - 1) / b; }

extern "C" void kernel_launch(void* const* d_in, const int* in_sizes, int n_in,
                              void* d_out, int out_size, void* d_ws, size_t ws_size,
                              hipStream_t stream) {
    const float* x_gene = (const float*)d_in[0];
    const float* x_dis  = (const float*)d_in[1];
    const int* e1s = (const int*)d_in[2];
    const int* e1d = (const int*)d_in[3];
    const int* e2s = (const int*)d_in[4];
    const int* e2d = (const int*)d_in[5];
    const float *Wg = (const float*)d_in[6],  *bg = (const float*)d_in[7];
    const float *gg = (const float*)d_in[8],  *betag = (const float*)d_in[9];
    const float *Wd = (const float*)d_in[10], *bd = (const float*)d_in[11];
    const float *gd = (const float*)d_in[12], *betad = (const float*)d_in[13];
    const float *W1s = (const float*)d_in[14], *W1d = (const float*)d_in[15];
    const float *a1s = (const float*)d_in[16], *a1d = (const float*)d_in[17];
    const float *b1  = (const float*)d_in[18];
    const float *W2s = (const float*)d_in[19], *W2d = (const float*)d_in[20];
    const float *a2s = (const float*)d_in[21], *a2d = (const float*)d_in[22];
    const float *b2  = (const float*)d_in[23];

    float* gene_f = (float*)d_out;                         // [N_GENE,128]
    float* dis_f  = (float*)d_out + (size_t)N_GENE * 128;  // [N_DIS,128]

    char* p = (char*)d_ws;
    auto alloc = [&](size_t bytes) {
        char* r = p;
        p += (bytes + 255) & ~(size_t)255;
        return r;
    };
    u16*   xs_buf  = (u16*)  alloc((size_t)N_GENE * 512 * 2);
    u16*   gene_bf = (u16*)  alloc((size_t)cdiv(N_GENE, 16) * 2048 * 2);
    u16*   dis_bf  = (u16*)  alloc((size_t)cdiv(N_DIS, 16) * 2048 * 2);
    float* ls_buf  = (float*)alloc((size_t)N_GENE * 4 * 4);
    float* ld_buf  = (float*)alloc((size_t)N_GENE * 4 * 4);
    float* weff    = (float*)alloc(512 * 4);
    float* stats   = (float*)alloc(256 * 4);
    int*   deg     = (int*)  alloc((size_t)N_GENE * 4);
    int*   offs    = (int*)  alloc((size_t)(N_GENE + 1) * 4);
    int*   cursor  = (int*)  alloc((size_t)N_GENE * 4);
    int*   bsum    = (int*)  alloc(256 * 4);
    int*   esrc    = (int*)  alloc((size_t)(E_EDGES + N_GENE) * 4);
    u16*   Wgt  = (u16*)alloc((size_t)8 * 16 * 512 * 2);   // [8nt][16kc][512]
    u16*   Wdt  = (u16*)alloc((size_t)8 * 8 * 512 * 2);    // [8nt][8kc][512]
    u16*   W1st = (u16*)alloc((size_t)32 * 4 * 512 * 2);   // [32nt][4kc][512]
    u16*   W2st = (u16*)alloc((size_t)32 * 4 * 512 * 2);

    const int NB = cdiv(N_GENE, 256);  // 196

    // ---- weight pack to fragment-major bf16 ----
    pack_b<<<cdiv(128 * 64, 256), 256, 0, stream>>>(Wg,  Wgt,  512, 128);
    pack_b<<<cdiv(128 * 32, 256), 256, 0, stream>>>(Wd,  Wdt,  256, 128);
    pack_b<<<cdiv(512 * 16, 256), 256, 0, stream>>>(W1s, W1st, 128, 512);
    pack_b<<<cdiv(512 * 16, 256), 256, 0, stream>>>(W2s, W2st, 128, 512);

    // ---- encode gene ----
    zero_kernel<<<1, 256, 0, stream>>>((int*)stats, 256);
    gemm_lds<512, false, true, false><<<dim3(cdiv(N_GENE, 64), 1), 256, 0, stream>>>(
        x_gene, Wgt, bg, gene_f, N_GENE, 128);
    col_stats<<<512, 128, 0, stream>>>(gene_f, N_GENE, stats);
    bn_apply<<<cdiv(N_GENE * 16, 256), 256, 0, stream>>>(gene_f, stats, gg, betag, nullptr, N_GENE);

    // ---- encode dis ----
    zero_kernel<<<1, 256, 0, stream>>>((int*)stats, 256);
    gemm_lds<256, false, true, false><<<dim3(cdiv(N_DIS, 64), 1), 256, 0, stream>>>(
        x_dis, Wdt, bd, dis_f, N_DIS, 128);
    col_stats<<<512, 128, 0, stream>>>(dis_f, N_DIS, stats);
    bn_apply<<<cdiv(N_DIS * 16, 256), 256, 0, stream>>>(dis_f, stats, gd, betad, dis_bf, N_DIS);

    // ---- relation 1: Disease -> Gene ----
    gemm_lds<128, true, false, true><<<dim3(cdiv(N_DIS, 64), 4), 256, 0, stream>>>(
        dis_bf, W1st, nullptr, xs_buf, N_DIS, 512);
    ls_kernel<<<cdiv(N_DIS, 4), 256, 0, stream>>>(xs_buf, a1s, ls_buf, N_DIS);
    weff_kernel<<<2, 256, 0, stream>>>(W1d, a1d, weff);
    ld_kernel<<<cdiv(N_GENE, 4), 256, 0, stream>>>(gene_f, weff, ld_buf, N_GENE);
    zero_kernel<<<cdiv(N_GENE, 256), 256, 0, stream>>>(deg, N_GENE);
    count_edges<<<cdiv(E_EDGES + N_DIS, 256), 256, 0, stream>>>(e1s, e1d, E_EDGES, N_DIS, deg);
    block_sum<<<NB, 256, 0, stream>>>(deg, bsum, N_GENE);
    scan_bsum<<<1, 256, 0, stream>>>(bsum, NB, &offs[N_GENE]);
    scan_final<<<NB, 256, 0, stream>>>(deg, bsum, offs, cursor, N_GENE);
    scatter_edges<<<cdiv(E_EDGES + N_DIS, 256), 256, 0, stream>>>(e1s, e1d, E_EDGES, N_DIS, cursor, esrc);
    gat_kernel<<<cdiv(N_GENE, 4), 256, 0, stream>>>(offs, esrc, ls_buf, ld_buf, xs_buf, b1, gene_f, gene_bf, N_GENE);

    // ---- relation 2: Gene -> Gene ----
    gemm_lds<128, true, false, true><<<dim3(cdiv(N_GENE, 64), 4), 256, 0, stream>>>(
        gene_bf, W2st, nullptr, xs_buf, N_GENE, 512);
    ls_kernel<<<cdiv(N_GENE, 4), 256, 0, stream>>>(xs_buf, a2s, ls_buf, N_GENE);
    weff_kernel<<<2, 256, 0, stream>>>(W2d, a2d, weff);
    ld_kernel<<<cdiv(N_GENE, 4), 256, 0, stream>>>(gene_f, weff, ld_buf, N_GENE);
    zero_kernel<<<cdiv(N_GENE, 256), 256, 0, stream>>>(deg, N_GENE);
    count_edges<<<cdiv(E_EDGES + N_GENE, 256), 256, 0, stream>>>(e2s, e2d, E_EDGES, N_GENE, deg);
    block_sum<<<NB, 256, 0, stream>>>(deg, bsum, N_GENE);
    scan_bsum<<<1, 256, 0, stream>>>(bsum, NB, &offs[N_GENE]);
    scan_final<<<NB, 256, 0, stream>>>(deg, bsum, offs, cursor, N_GENE);
    scatter_edges<<<cdiv(E_EDGES + N_GENE, 256), 256, 0, stream>>>(e2s, e2d, E_EDGES, N_GENE, cursor, esrc);
    gat_kernel<<<cdiv(N_GENE, 4), 256, 0, stream>>>(offs, esrc, ls_buf, ld_buf, xs_buf, b2, gene_f, nullptr, N_GENE);
}

// Round 2
// 593.098 us; speedup vs baseline: 1.0353x; 1.0146x over previous
//
#include <hip/hip_runtime.h>
#include <hip/hip_bf16.h>
#include <math.h>

#define N_GENE 50000
#define N_DIS  25000
#define F_GENE 512
#define F_DIS  256
#define E_EDGES 150000
#define BN_EPS 1e-5f

typedef unsigned short u16;
typedef unsigned int u32;
typedef short s16x8 __attribute__((ext_vector_type(8)));
typedef float f32x4 __attribute__((ext_vector_type(4)));

__device__ __forceinline__ u16 f2bf(float f) {
    union { float f; unsigned u; } c; c.f = f;
    unsigned u = c.u;
    unsigned rounding = 0x7FFFu + ((u >> 16) & 1u);
    return (u16)((u + rounding) >> 16);
}
__device__ __forceinline__ void load_bf16x8(const u16* p, float* f) {
    uint4 q = *reinterpret_cast<const uint4*>(p);
    unsigned w0 = q.x, w1 = q.y, w2 = q.z, w3 = q.w;
    f[0] = __uint_as_float(w0 << 16); f[1] = __uint_as_float(w0 & 0xffff0000u);
    f[2] = __uint_as_float(w1 << 16); f[3] = __uint_as_float(w1 & 0xffff0000u);
    f[4] = __uint_as_float(w2 << 16); f[5] = __uint_as_float(w2 & 0xffff0000u);
    f[6] = __uint_as_float(w3 << 16); f[7] = __uint_as_float(w3 & 0xffff0000u);
}

// async global->LDS, 16B per lane; LDS dest is wave-uniform base + lane*16
__device__ __forceinline__ void gload_lds16(const u16* g, u16* l) {
    __builtin_amdgcn_global_load_lds(
        (const __attribute__((address_space(1))) u32*)g,
        (__attribute__((address_space(3))) u32*)l, 16, 0, 0);
}

// ---- B pack helper: W f32 [K][N] -> fragment-major bf16 Bp[nt][KC][64][8]
__device__ __forceinline__ void pack_one(const float* __restrict__ W, u16* __restrict__ Bp,
                                         int K, int N, int i) {
    int K8 = K >> 3;
    int n = i / K8, ko = i - n * K8;
    int k0 = ko * 8;
    int nt = n >> 4, mr = n & 15, kc = k0 >> 5, quad = (k0 >> 3) & 3;
    u16 tmp[8];
#pragma unroll
    for (int j = 0; j < 8; j++) tmp[j] = f2bf(W[(size_t)(k0 + j) * N + n]);
    *reinterpret_cast<uint4*>(&Bp[((size_t)(nt * (K >> 5) + kc) * 64 + quad * 16 + mr) * 8]) =
        *reinterpret_cast<const uint4*>(tmp);
}

// ---- one front-kernel: all weight packs + all zero-fills + both weff vectors ----
__global__ void prep(const float* __restrict__ Wg, const float* __restrict__ Wd,
                     const float* __restrict__ W1s, const float* __restrict__ W2s,
                     u16* __restrict__ Wgt, u16* __restrict__ Wdt,
                     u16* __restrict__ W1st, u16* __restrict__ W2st,
                     float* __restrict__ stats_g, float* __restrict__ stats_d,
                     int* __restrict__ deg1, int* __restrict__ deg2,
                     const float* __restrict__ W1d, const float* __restrict__ a1d,
                     const float* __restrict__ W2d, const float* __restrict__ a2d,
                     float* __restrict__ weff) {
    int i = blockIdx.x * 256 + threadIdx.x;
    if (i < 8192) { pack_one(Wg, Wgt, 512, 128, i); return; }
    i -= 8192;
    if (i < 4096) { pack_one(Wd, Wdt, 256, 128, i); return; }
    i -= 4096;
    if (i < 8192) { pack_one(W1s, W1st, 128, 512, i); return; }
    i -= 8192;
    if (i < 8192) { pack_one(W2s, W2st, 128, 512, i); return; }
    i -= 8192;
    if (i < 256) { stats_g[i] = 0.f; return; }
    i -= 256;
    if (i < 256) { stats_d[i] = 0.f; return; }
    i -= 256;
    if (i < N_GENE) { deg1[i] = 0; return; }
    i -= N_GENE;
    if (i < N_GENE) { deg2[i] = 0; return; }
    i -= N_GENE;
    if (i < 1024) {
        int rel = i >> 9, tt = i & 511;
        int h = tt >> 7, k = tt & 127;
        const float* Wp = rel ? W2d : W1d;
        const float* ap = rel ? a2d : a1d;
        float s = 0.f;
        for (int c = 0; c < 128; c++) s += Wp[k * 512 + h * 128 + c] * ap[h * 128 + c];
        weff[rel * 512 + h * 128 + k] = s;
    }
}

// ---- GEMM, software-pipelined (dbuf LDS B via global_load_lds + 1-chunk-ahead A regs,
// ---- counted vmcnt). Optional fused epilogues: BN stats (encode) / ls attention dot (rel).
template <int K, bool A_FRAG, bool RELU_BIAS, bool OUT_BF16, bool FUSE_STATS, bool FUSE_LS>
__global__ __launch_bounds__(256) void gemm_lds(const void* __restrict__ Ap,
                                                const u16* __restrict__ Bp,
                                                const float* __restrict__ bias,
                                                void* __restrict__ outp, int M, int NFULL,
                                                float* __restrict__ stats,
                                                const float* __restrict__ as_,
                                                float* __restrict__ ls_out) {
    constexpr int KC = K / 32;          // 16 / 8 / 4
    constexpr int CK = 2;               // kc per chunk
    constexpr int NCH = KC / CK;        // 8 / 4 / 2  (always even)
    __shared__ u16 Bs[2][8 * CK * 64 * 8];   // 2 x 16KB
    __shared__ float sstat[256];
    const int wave = threadIdx.x >> 6;
    const int lane = threadIdx.x & 63;
    const int mrow = lane & 15;
    const int quad = lane >> 4;
    const int m0 = (blockIdx.x * 4 + wave) * 16;
    const int n0 = blockIdx.y * 128;
    const int arow = (m0 + mrow < M) ? m0 + mrow : M - 1;
    const int rt = (m0 >> 4) < ((M + 15) >> 4) ? (m0 >> 4) : ((M + 15) >> 4) - 1;
    const u16* bslab = Bp + (size_t)(n0 >> 4) * KC * 512;  // 512 u16 per frag

    if constexpr (FUSE_STATS) sstat[threadIdx.x] = 0.f;  // 256 threads exactly

    f32x4 acc[8];
#pragma unroll
    for (int t = 0; t < 8; t++) acc[t] = (f32x4){0.f, 0.f, 0.f, 0.f};

    struct ARegs { float4 f[2 * CK]; s16x8 s[CK]; };
    ARegs A0, A1;

    auto stageB = [&](int c, int b) {
#pragma unroll
        for (int q = 0; q < 2 * CK; q++) {
            int fi = wave * 2 * CK + q;
            int t = fi / CK, kcp = fi % CK;
            const u16* g = bslab + ((size_t)(t * KC + c * CK + kcp) * 64 + lane) * 8;
            gload_lds16(g, &Bs[b][(size_t)fi * 512]);
        }
    };
    auto loadA = [&](int c, ARegs& A) {
        if constexpr (A_FRAG) {
#pragma unroll
            for (int kcp = 0; kcp < CK; kcp++)
                A.s[kcp] = *reinterpret_cast<const s16x8*>(
                    (const u16*)Ap + ((size_t)(rt * KC + c * CK + kcp) * 64 + lane) * 8);
        } else {
#pragma unroll
            for (int kcp = 0; kcp < CK; kcp++) {
                const float* ap = (const float*)Ap + (size_t)arow * K + (c * CK + kcp) * 32 + quad * 8;
                A.f[2 * kcp]     = *reinterpret_cast<const float4*>(ap);
                A.f[2 * kcp + 1] = *reinterpret_cast<const float4*>(ap + 4);
            }
        }
    };
    auto compute = [&](const u16* Bsb, const ARegs& A) {
#pragma unroll
        for (int kcp = 0; kcp < CK; kcp++) {
            s16x8 af;
            if constexpr (A_FRAG) {
                af = A.s[kcp];
            } else {
                const float4 lo = A.f[2 * kcp], hi = A.f[2 * kcp + 1];
                af[0] = (short)f2bf(lo.x); af[1] = (short)f2bf(lo.y);
                af[2] = (short)f2bf(lo.z); af[3] = (short)f2bf(lo.w);
                af[4] = (short)f2bf(hi.x); af[5] = (short)f2bf(hi.y);
                af[6] = (short)f2bf(hi.z); af[7] = (short)f2bf(hi.w);
            }
#pragma unroll
            for (int t = 0; t < 8; t++) {
                const s16x8 bfr = *reinterpret_cast<const s16x8*>(
                    &Bsb[((size_t)(t * CK + kcp) * 64 + lane) * 8]);
                acc[t] = __builtin_amdgcn_mfma_f32_16x16x32_bf16(af, bfr, acc[t], 0, 0, 0);
            }
        }
    };

    // per-wave outstanding after issuing next chunk: stage(2*CK=4) + loadA(4 f32 / 2 frag)
#define FENCE_N() do { if constexpr (A_FRAG) asm volatile("s_waitcnt vmcnt(6)" ::: "memory"); \
                       else                  asm volatile("s_waitcnt vmcnt(8)" ::: "memory"); } while (0)
#define FENCE_0() asm volatile("s_waitcnt vmcnt(0)" ::: "memory")
#define LGKM0()   asm volatile("s_waitcnt lgkmcnt(0)" ::: "memory")
#define BAR()     asm volatile("s_barrier" ::: "memory")

    stageB(0, 0);
    loadA(0, A0);
    for (int cc = 0; cc < NCH / 2; ++cc) {
        stageB(2 * cc + 1, 1);
        loadA(2 * cc + 1, A1);
        FENCE_N();
        BAR();
        compute(&Bs[0][0], A0);
        LGKM0();
        BAR();
        if (cc + 1 < NCH / 2) {
            stageB(2 * cc + 2, 0);
            loadA(2 * cc + 2, A0);
            FENCE_N();
        } else {
            FENCE_0();
        }
        BAR();
        compute(&Bs[1][0], A1);
        LGKM0();
        BAR();
    }
#undef FENCE_N
#undef FENCE_0
#undef LGKM0
#undef BAR

    float asv[8];
    if constexpr (FUSE_LS) {
        const int h = blockIdx.y;
#pragma unroll
        for (int t = 0; t < 8; t++) asv[t] = as_[h * 128 + t * 16 + mrow];
    }
    float lsp[4] = {0.f, 0.f, 0.f, 0.f};

#pragma unroll
    for (int t = 0; t < 8; t++) {
        int col = n0 + t * 16 + mrow;
        float sv = 0.f, sv2 = 0.f;
#pragma unroll
        for (int r = 0; r < 4; r++) {
            int orow = m0 + quad * 4 + r;
            if (orow < M) {
                float v = acc[t][r];
                if (RELU_BIAS) v = fmaxf(v + bias[col], 0.f);
                if (OUT_BF16)
                    ((u16*)outp)[(size_t)orow * NFULL + col] = f2bf(v);
                else
                    ((float*)outp)[(size_t)orow * NFULL + col] = v;
                if constexpr (FUSE_STATS) { sv += v; sv2 += v * v; }
                if constexpr (FUSE_LS) lsp[r] += v * asv[t];
            }
        }
        if constexpr (FUSE_STATS) {
            sv  += __shfl_xor(sv, 16, 64);  sv  += __shfl_xor(sv, 32, 64);
            sv2 += __shfl_xor(sv2, 16, 64); sv2 += __shfl_xor(sv2, 32, 64);
            if (quad == 0) {
                atomicAdd(&sstat[t * 16 + mrow], sv);
                atomicAdd(&sstat[128 + t * 16 + mrow], sv2);
            }
        }
    }
    if constexpr (FUSE_LS) {
        const int h = blockIdx.y;
#pragma unroll
        for (int r = 0; r < 4; r++) {
            float p = lsp[r];
            p += __shfl_xor(p, 1, 64); p += __shfl_xor(p, 2, 64);
            p += __shfl_xor(p, 4, 64); p += __shfl_xor(p, 8, 64);
            int orow = m0 + quad * 4 + r;
            if (mrow == 0 && orow < M) ls_out[orow * 4 + h] = p;
        }
    }
    if constexpr (FUSE_STATS) {
        __syncthreads();
        atomicAdd(&stats[threadIdx.x], sstat[threadIdx.x]);  // 256 threads
    }
}

// bn in place; optional bf16 fragment-major mirror; optional fused ld (dst attention dot)
__global__ void bn_apply(float* __restrict__ X, const float* __restrict__ stats,
                         const float* __restrict__ gamma, const float* __restrict__ beta,
                         u16* __restrict__ mirror, const float* __restrict__ weff,
                         float* __restrict__ ld_out, int M) {
    int i = blockIdx.x * 256 + threadIdx.x;   // M*16 threads, 8 cols each
    if (i >= M * 16) return;
    int row = i >> 4, cg = i & 15;
    float inv_m = 1.0f / (float)M;
    float4 lo = *reinterpret_cast<const float4*>(&X[(size_t)row * 128 + cg * 8]);
    float4 hi = *reinterpret_cast<const float4*>(&X[(size_t)row * 128 + cg * 8 + 4]);
    float v[8] = {lo.x, lo.y, lo.z, lo.w, hi.x, hi.y, hi.z, hi.w};
    u16 mb[8];
#pragma unroll
    for (int e = 0; e < 8; e++) {
        int col = cg * 8 + e;
        float mu = stats[col] * inv_m;
        float var = stats[128 + col] * inv_m - mu * mu;
        v[e] = gamma[col] * (v[e] - mu) * rsqrtf(var + BN_EPS) + beta[col];
        mb[e] = f2bf(v[e]);
    }
    *reinterpret_cast<float4*>(&X[(size_t)row * 128 + cg * 8]) = (float4){v[0], v[1], v[2], v[3]};
    *reinterpret_cast<float4*>(&X[(size_t)row * 128 + cg * 8 + 4]) = (float4){v[4], v[5], v[6], v[7]};
    if (mirror) {
        int kc = cg >> 2, quad = cg & 3, ml = quad * 16 + (row & 15), rt = row >> 4;
        *reinterpret_cast<uint4*>(&mirror[((size_t)(rt * 4 + kc) * 64 + ml) * 8]) =
            *reinterpret_cast<const uint4*>(mb);
    }
    if (ld_out) {
#pragma unroll
        for (int h = 0; h < 4; h++) {
            float p = 0.f;
#pragma unroll
            for (int e = 0; e < 8; e++) p += v[e] * weff[h * 128 + cg * 8 + e];
            p += __shfl_xor(p, 1, 64); p += __shfl_xor(p, 2, 64);
            p += __shfl_xor(p, 4, 64); p += __shfl_xor(p, 8, 64);
            if (cg == 0) ld_out[row * 4 + h] = p;
        }
    }
}

// ---------------- CSR build (both relations) ----------------
__global__ void count_both(const int* __restrict__ e1s, const int* __restrict__ e1d,
                           const int* __restrict__ e2s, const int* __restrict__ e2d,
                           int* __restrict__ deg1, int* __restrict__ deg2) {
    int i = blockIdx.x * 256 + threadIdx.x;
    if (i < E_EDGES + N_DIS) {
        int d;
        if (i < E_EDGES) { int s = e1s[i]; d = e1d[i]; if (s == d) return; }
        else d = i - E_EDGES;
        atomicAdd(&deg1[d], 1);
        return;
    }
    i -= E_EDGES + N_DIS;
    if (i < E_EDGES + N_GENE) {
        int d;
        if (i < E_EDGES) { int s = e2s[i]; d = e2d[i]; if (s == d) return; }
        else d = i - E_EDGES;
        atomicAdd(&deg2[d], 1);
    }
}

__global__ __launch_bounds__(1024) void scan_both(const int* __restrict__ deg1, int* __restrict__ offs1, int* __restrict__ cur1,
                                                  const int* __restrict__ deg2, int* __restrict__ offs2, int* __restrict__ cur2) {
    const int* deg = blockIdx.x ? deg2 : deg1;
    int* offs = blockIdx.x ? offs2 : offs1;
    int* cur  = blockIdx.x ? cur2  : cur1;
    const int n = N_GENE;
    __shared__ int sh[1024];
    int tid = threadIdx.x;
    const int chunk = (n + 1023) >> 10;   // 49
    int base = tid * chunk;
    int s = 0;
    for (int j = 0; j < chunk; j++) { int i = base + j; if (i < n) s += deg[i]; }
    sh[tid] = s;
    __syncthreads();
    for (int off = 1; off < 1024; off <<= 1) {
        int t = (tid >= off) ? sh[tid - off] : 0;
        __syncthreads();
        sh[tid] += t;
        __syncthreads();
    }
    int ex = tid ? sh[tid - 1] : 0;
    for (int j = 0; j < chunk; j++) {
        int i = base + j;
        if (i < n) { offs[i] = ex; cur[i] = ex; ex += deg[i]; }
    }
    if (tid == 1023) offs[n] = sh[1023];
}

__global__ void scatter_both(const int* __restrict__ e1s, const int* __restrict__ e1d,
                             const int* __restrict__ e2s, const int* __restrict__ e2d,
                             int* __restrict__ cur1, int* __restrict__ cur2,
                             int* __restrict__ esrc1, int* __restrict__ esrc2) {
    int i = blockIdx.x * 256 + threadIdx.x;
    if (i < E_EDGES + N_DIS) {
        int s, d;
        if (i < E_EDGES) { s = e1s[i]; d = e1d[i]; if (s == d) return; }
        else { s = i - E_EDGES; d = s; }
        esrc1[atomicAdd(&cur1[d], 1)] = s;
        return;
    }
    i -= E_EDGES + N_DIS;
    if (i < E_EDGES + N_GENE) {
        int s, d;
        if (i < E_EDGES) { s = e2s[i]; d = e2d[i]; if (s == d) return; }
        else { s = i - E_EDGES; d = s; }
        esrc2[atomicAdd(&cur2[d], 1)] = s;
    }
}

// ---- GAT aggregation: one wave per dst node; updates xdst_out in place ----
// optional fused: ld for NEXT relation (from updated row), bf16 fragment-major mirror
__global__ void gat_kernel(const int* __restrict__ offs, const int* __restrict__ esrc,
                           const float* __restrict__ ls, const float* __restrict__ ld,
                           const u16* __restrict__ xs, const float* __restrict__ bias,
                           float* __restrict__ xdst_out, u16* __restrict__ mirror,
                           const float* __restrict__ weff2, float* __restrict__ ld2_out,
                           int n_dst) {
    int wid = (blockIdx.x * blockDim.x + threadIdx.x) >> 6;
    int lane = threadIdx.x & 63;
    if (wid >= n_dst) return;
    int h = lane >> 4;
    int beg = offs[wid], end = offs[wid + 1];
    float ldv = ld[wid * 4 + h];
    float m = -INFINITY;
    for (int j = beg; j < end; j++) {
        int s = esrc[j];
        float l = ls[s * 4 + h] + ldv;
        l = l > 0.f ? l : 0.2f * l;
        m = fmaxf(m, l);
    }
    float denom = 0.f;
    float acc[8] = {0.f, 0.f, 0.f, 0.f, 0.f, 0.f, 0.f, 0.f};
    for (int j = beg; j < end; j++) {
        int s = esrc[j];
        float l = ls[s * 4 + h] + ldv;
        l = l > 0.f ? l : 0.2f * l;
        float p = __expf(l - m);
        denom += p;
        float xv[8];
        load_bf16x8(xs + (size_t)s * 512 + lane * 8, xv);
        #pragma unroll
        for (int k = 0; k < 8; k++) acc[k] += p * xv[k];
    }
    float dinv = denom > 0.f ? 1.f / denom : 1.f;
    #pragma unroll
    for (int k = 0; k < 8; k++) {
        float v = acc[k] * dinv;
        v += __shfl_xor(v, 16, 64);
        v += __shfl_xor(v, 32, 64);
        acc[k] = v * 0.25f;
    }
    if (lane < 16) {
        int c0 = lane * 8;
        float vout[8];
        #pragma unroll
        for (int k = 0; k < 8; k++) {
            vout[k] = xdst_out[(size_t)wid * 128 + c0 + k] + acc[k] + bias[c0 + k];
            xdst_out[(size_t)wid * 128 + c0 + k] = vout[k];
        }
        if (mirror) {
            unsigned pk[4];
            #pragma unroll
            for (int kk = 0; kk < 4; kk++)
                pk[kk] = (unsigned)f2bf(vout[2 * kk]) | ((unsigned)f2bf(vout[2 * kk + 1]) << 16);
            int kc = lane >> 2, quad = lane & 3, ml = quad * 16 + (wid & 15), rt = wid >> 4;
            *reinterpret_cast<uint4*>(&mirror[((size_t)(rt * 4 + kc) * 64 + ml) * 8]) =
                *reinterpret_cast<const uint4*>(pk);
        }
        if (weff2) {
            #pragma unroll
            for (int hh = 0; hh < 4; hh++) {
                float p = 0.f;
                #pragma unroll
                for (int k = 0; k < 8; k++) p += vout[k] * weff2[hh * 128 + c0 + k];
                p += __shfl_xor(p, 1, 64); p += __shfl_xor(p, 2, 64);
                p += __shfl_xor(p, 4, 64); p += __shfl_xor(p, 8, 64);
                if (lane == 0) ld2_out[wid * 4 + hh] = p;
            }
        }
    }
}

static inline int cdiv(int a, int b) { return (a + b - 1) / b; }

extern "C" void kernel_launch(void* const* d_in, const int* in_sizes, int n_in,
                              void* d_out, int out_size, void* d_ws, size_t ws_size,
                              hipStream_t stream) {
    const float* x_gene = (const float*)d_in[0];
    const float* x_dis  = (const float*)d_in[1];
    const int* e1s = (const int*)d_in[2];
    const int* e1d = (const int*)d_in[3];
    const int* e2s = (const int*)d_in[4];
    const int* e2d = (const int*)d_in[5];
    const float *Wg = (const float*)d_in[6],  *bg = (const float*)d_in[7];
    const float *gg = (const float*)d_in[8],  *betag = (const float*)d_in[9];
    const float *Wd = (const float*)d_in[10], *bd = (const float*)d_in[11];
    const float *gd = (const float*)d_in[12], *betad = (const float*)d_in[13];
    const float *W1s = (const float*)d_in[14], *W1d = (const float*)d_in[15];
    const float *a1s = (const float*)d_in[16], *a1d = (const float*)d_in[17];
    const float *b1  = (const float*)d_in[18];
    const float *W2s = (const float*)d_in[19], *W2d = (const float*)d_in[20];
    const float *a2s = (const float*)d_in[21], *a2d = (const float*)d_in[22];
    const float *b2  = (const float*)d_in[23];

    float* gene_f = (float*)d_out;                         // [N_GENE,128]
    float* dis_f  = (float*)d_out + (size_t)N_GENE * 128;  // [N_DIS,128]

    char* p = (char*)d_ws;
    auto alloc = [&](size_t bytes) {
        char* r = p;
        p += (bytes + 255) & ~(size_t)255;
        return r;
    };
    u16*   xs_buf  = (u16*)  alloc((size_t)N_GENE * 512 * 2);
    u16*   gene_bf = (u16*)  alloc((size_t)cdiv(N_GENE, 16) * 2048 * 2);
    u16*   dis_bf  = (u16*)  alloc((size_t)cdiv(N_DIS, 16) * 2048 * 2);
    float* ls_buf  = (float*)alloc((size_t)N_GENE * 4 * 4);
    float* ld1_buf = (float*)alloc((size_t)N_GENE * 4 * 4);
    float* ld2_buf = (float*)alloc((size_t)N_GENE * 4 * 4);
    float* weff    = (float*)alloc(1024 * 4);              // [rel1:512 | rel2:512]
    float* stats_g = (float*)alloc(256 * 4);
    float* stats_d = (float*)alloc(256 * 4);
    int*   deg1    = (int*)  alloc((size_t)N_GENE * 4);
    int*   deg2    = (int*)  alloc((size_t)N_GENE * 4);
    int*   offs1   = (int*)  alloc((size_t)(N_GENE + 1) * 4);
    int*   offs2   = (int*)  alloc((size_t)(N_GENE + 1) * 4);
    int*   cur1    = (int*)  alloc((size_t)N_GENE * 4);
    int*   cur2    = (int*)  alloc((size_t)N_GENE * 4);
    int*   esrc1   = (int*)  alloc((size_t)(E_EDGES + N_GENE) * 4);
    int*   esrc2   = (int*)  alloc((size_t)(E_EDGES + N_GENE) * 4);
    u16*   Wgt  = (u16*)alloc((size_t)8 * 16 * 512 * 2);   // [8nt][16kc][512]
    u16*   Wdt  = (u16*)alloc((size_t)8 * 8 * 512 * 2);    // [8nt][8kc][512]
    u16*   W1st = (u16*)alloc((size_t)32 * 4 * 512 * 2);   // [32nt][4kc][512]
    u16*   W2st = (u16*)alloc((size_t)32 * 4 * 512 * 2);

    // ---- front: packs + zeros + weff (1 kernel), then CSR for both relations ----
    const int PREP_T = 8192 + 4096 + 8192 + 8192 + 256 + 256 + N_GENE + N_GENE + 1024;
    prep<<<cdiv(PREP_T, 256), 256, 0, stream>>>(Wg, Wd, W1s, W2s, Wgt, Wdt, W1st, W2st,
                                                stats_g, stats_d, deg1, deg2,
                                                W1d, a1d, W2d, a2d, weff);
    const int EB = cdiv((E_EDGES + N_DIS) + (E_EDGES + N_GENE), 256);
    count_both<<<EB, 256, 0, stream>>>(e1s, e1d, e2s, e2d, deg1, deg2);
    scan_both<<<2, 1024, 0, stream>>>(deg1, offs1, cur1, deg2, offs2, cur2);
    scatter_both<<<EB, 256, 0, stream>>>(e1s, e1d, e2s, e2d, cur1, cur2, esrc1, esrc2);

    // ---- encode gene (stats fused into GEMM; ld1 fused into bn) ----
    gemm_lds<512, false, true, false, true, false><<<dim3(cdiv(N_GENE, 64), 1), 256, 0, stream>>>(
        x_gene, Wgt, bg, gene_f, N_GENE, 128, stats_g, nullptr, nullptr);
    bn_apply<<<cdiv(N_GENE * 16, 256), 256, 0, stream>>>(gene_f, stats_g, gg, betag,
                                                         nullptr, weff, ld1_buf, N_GENE);

    // ---- encode dis ----
    gemm_lds<256, false, true, false, true, false><<<dim3(cdiv(N_DIS, 64), 1), 256, 0, stream>>>(
        x_dis, Wdt, bd, dis_f, N_DIS, 128, stats_d, nullptr, nullptr);
    bn_apply<<<cdiv(N_DIS * 16, 256), 256, 0, stream>>>(dis_f, stats_d, gd, betad,
                                                        dis_bf, nullptr, nullptr, N_DIS);

    // ---- relation 1: Disease -> Gene (ls fused into GEMM; ld2 fused into gat) ----
    gemm_lds<128, true, false, true, false, true><<<dim3(cdiv(N_DIS, 64), 4), 256, 0, stream>>>(
        dis_bf, W1st, nullptr, xs_buf, N_DIS, 512, nullptr, a1s, ls_buf);
    gat_kernel<<<cdiv(N_GENE, 4), 256, 0, stream>>>(offs1, esrc1, ls_buf, ld1_buf, xs_buf, b1,
                                                    gene_f, gene_bf, weff + 512, ld2_buf, N_GENE);

    // ---- relation 2: Gene -> Gene ----
    gemm_lds<128, true, false, true, false, true><<<dim3(cdiv(N_GENE, 64), 4), 256, 0, stream>>>(
        gene_bf, W2st, nullptr, xs_buf, N_GENE, 512, nullptr, a2s, ls_buf);
    gat_kernel<<<cdiv(N_GENE, 4), 256, 0, stream>>>(offs2, esrc2, ls_buf, ld2_buf, xs_buf, b2,
                                                    gene_f, nullptr, nullptr, nullptr, N_GENE);
}

// Round 3
// 476.534 us; speedup vs baseline: 1.2886x; 1.2446x over previous
//
#include <hip/hip_runtime.h>
#include <hip/hip_bf16.h>
#include <math.h>

#define N_GENE 50000
#define N_DIS  25000
#define F_GENE 512
#define F_DIS  256
#define E_EDGES 150000
#define BN_EPS 1e-5f

typedef unsigned short u16;
typedef unsigned int u32;
typedef short s16x8 __attribute__((ext_vector_type(8)));
typedef float f32x4 __attribute__((ext_vector_type(4)));

__device__ __forceinline__ u16 f2bf(float f) {
    union { float f; unsigned u; } c; c.f = f;
    unsigned u = c.u;
    unsigned rounding = 0x7FFFu + ((u >> 16) & 1u);
    return (u16)((u + rounding) >> 16);
}
__device__ __forceinline__ void load_bf16x8(const u16* p, float* f) {
    uint4 q = *reinterpret_cast<const uint4*>(p);
    unsigned w0 = q.x, w1 = q.y, w2 = q.z, w3 = q.w;
    f[0] = __uint_as_float(w0 << 16); f[1] = __uint_as_float(w0 & 0xffff0000u);
    f[2] = __uint_as_float(w1 << 16); f[3] = __uint_as_float(w1 & 0xffff0000u);
    f[4] = __uint_as_float(w2 << 16); f[5] = __uint_as_float(w2 & 0xffff0000u);
    f[6] = __uint_as_float(w3 << 16); f[7] = __uint_as_float(w3 & 0xffff0000u);
}

// async global->LDS, 16B per lane; LDS dest is wave-uniform base + lane*16
__device__ __forceinline__ void gload_lds16(const u16* g, u16* l) {
    __builtin_amdgcn_global_load_lds(
        (const __attribute__((address_space(1))) u32*)g,
        (__attribute__((address_space(3))) u32*)l, 16, 0, 0);
}

// ---- B pack helper: W f32 [K][N] -> fragment-major bf16 Bp[nt][KC][64][8]
__device__ __forceinline__ void pack_one(const float* __restrict__ W, u16* __restrict__ Bp,
                                         int K, int N, int i) {
    int K8 = K >> 3;
    int n = i / K8, ko = i - n * K8;
    int k0 = ko * 8;
    int nt = n >> 4, mr = n & 15, kc = k0 >> 5, quad = (k0 >> 3) & 3;
    u16 tmp[8];
#pragma unroll
    for (int j = 0; j < 8; j++) tmp[j] = f2bf(W[(size_t)(k0 + j) * N + n]);
    *reinterpret_cast<uint4*>(&Bp[((size_t)(nt * (K >> 5) + kc) * 64 + quad * 16 + mr) * 8]) =
        *reinterpret_cast<const uint4*>(tmp);
}

// ---- one front-kernel: all weight packs + all zero-fills + both weff vectors ----
__global__ void prep(const float* __restrict__ Wg, const float* __restrict__ Wd,
                     const float* __restrict__ W1s, const float* __restrict__ W2s,
                     u16* __restrict__ Wgt, u16* __restrict__ Wdt,
                     u16* __restrict__ W1st, u16* __restrict__ W2st,
                     float* __restrict__ stats_g, float* __restrict__ stats_d,
                     int* __restrict__ deg1, int* __restrict__ deg2,
                     const float* __restrict__ W1d, const float* __restrict__ a1d,
                     const float* __restrict__ W2d, const float* __restrict__ a2d,
                     float* __restrict__ weff) {
    int i = blockIdx.x * 256 + threadIdx.x;
    if (i < 8192) { pack_one(Wg, Wgt, 512, 128, i); return; }
    i -= 8192;
    if (i < 4096) { pack_one(Wd, Wdt, 256, 128, i); return; }
    i -= 4096;
    if (i < 8192) { pack_one(W1s, W1st, 128, 512, i); return; }
    i -= 8192;
    if (i < 8192) { pack_one(W2s, W2st, 128, 512, i); return; }
    i -= 8192;
    if (i < 256) { stats_g[i] = 0.f; return; }
    i -= 256;
    if (i < 256) { stats_d[i] = 0.f; return; }
    i -= 256;
    if (i < N_GENE) { deg1[i] = 0; return; }
    i -= N_GENE;
    if (i < N_GENE) { deg2[i] = 0; return; }
    i -= N_GENE;
    if (i < 1024) {
        int rel = i >> 9, tt = i & 511;
        int h = tt >> 7, k = tt & 127;
        const float* Wp = rel ? W2d : W1d;
        const float* ap = rel ? a2d : a1d;
        float s = 0.f;
        for (int c = 0; c < 128; c++) s += Wp[k * 512 + h * 128 + c] * ap[h * 128 + c];
        weff[rel * 512 + h * 128 + k] = s;
    }
}

// ---- GEMM, software-pipelined (dbuf LDS B via global_load_lds + 1-chunk-ahead A regs,
// ---- counted vmcnt). Optional fused epilogues: BN stats (encode) / ls attention dot (rel).
template <int K, bool A_FRAG, bool RELU_BIAS, bool OUT_BF16, bool FUSE_STATS, bool FUSE_LS>
__global__ __launch_bounds__(256) void gemm_lds(const void* __restrict__ Ap,
                                                const u16* __restrict__ Bp,
                                                const float* __restrict__ bias,
                                                void* __restrict__ outp, int M, int NFULL,
                                                float* __restrict__ stats,
                                                const float* __restrict__ as_,
                                                float* __restrict__ ls_out) {
    constexpr int KC = K / 32;          // 16 / 8 / 4
    constexpr int CK = 2;               // kc per chunk
    constexpr int NCH = KC / CK;        // 8 / 4 / 2  (always even)
    __shared__ u16 Bs[2][8 * CK * 64 * 8];   // 2 x 16KB
    __shared__ float sstat[256];
    const int wave = threadIdx.x >> 6;
    const int lane = threadIdx.x & 63;
    const int mrow = lane & 15;
    const int quad = lane >> 4;
    const int m0 = (blockIdx.x * 4 + wave) * 16;
    const int n0 = blockIdx.y * 128;
    const int arow = (m0 + mrow < M) ? m0 + mrow : M - 1;
    const int rt = (m0 >> 4) < ((M + 15) >> 4) ? (m0 >> 4) : ((M + 15) >> 4) - 1;
    const u16* bslab = Bp + (size_t)(n0 >> 4) * KC * 512;  // 512 u16 per frag

    if constexpr (FUSE_STATS) sstat[threadIdx.x] = 0.f;  // 256 threads exactly

    f32x4 acc[8];
#pragma unroll
    for (int t = 0; t < 8; t++) acc[t] = (f32x4){0.f, 0.f, 0.f, 0.f};

    struct ARegs { float4 f[2 * CK]; s16x8 s[CK]; };
    ARegs A0, A1;

    auto stageB = [&](int c, int b) {
#pragma unroll
        for (int q = 0; q < 2 * CK; q++) {
            int fi = wave * 2 * CK + q;
            int t = fi / CK, kcp = fi % CK;
            const u16* g = bslab + ((size_t)(t * KC + c * CK + kcp) * 64 + lane) * 8;
            gload_lds16(g, &Bs[b][(size_t)fi * 512]);
        }
    };
    auto loadA = [&](int c, ARegs& A) {
        if constexpr (A_FRAG) {
#pragma unroll
            for (int kcp = 0; kcp < CK; kcp++)
                A.s[kcp] = *reinterpret_cast<const s16x8*>(
                    (const u16*)Ap + ((size_t)(rt * KC + c * CK + kcp) * 64 + lane) * 8);
        } else {
#pragma unroll
            for (int kcp = 0; kcp < CK; kcp++) {
                const float* ap = (const float*)Ap + (size_t)arow * K + (c * CK + kcp) * 32 + quad * 8;
                A.f[2 * kcp]     = *reinterpret_cast<const float4*>(ap);
                A.f[2 * kcp + 1] = *reinterpret_cast<const float4*>(ap + 4);
            }
        }
    };
    auto compute = [&](const u16* Bsb, const ARegs& A) {
#pragma unroll
        for (int kcp = 0; kcp < CK; kcp++) {
            s16x8 af;
            if constexpr (A_FRAG) {
                af = A.s[kcp];
            } else {
                const float4 lo = A.f[2 * kcp], hi = A.f[2 * kcp + 1];
                af[0] = (short)f2bf(lo.x); af[1] = (short)f2bf(lo.y);
                af[2] = (short)f2bf(lo.z); af[3] = (short)f2bf(lo.w);
                af[4] = (short)f2bf(hi.x); af[5] = (short)f2bf(hi.y);
                af[6] = (short)f2bf(hi.z); af[7] = (short)f2bf(hi.w);
            }
#pragma unroll
            for (int t = 0; t < 8; t++) {
                const s16x8 bfr = *reinterpret_cast<const s16x8*>(
                    &Bsb[((size_t)(t * CK + kcp) * 64 + lane) * 8]);
                acc[t] = __builtin_amdgcn_mfma_f32_16x16x32_bf16(af, bfr, acc[t], 0, 0, 0);
            }
        }
    };

    // per-wave outstanding after issuing next chunk: stage(2*CK=4) + loadA(4 f32 / 2 frag)
#define FENCE_N() do { if constexpr (A_FRAG) asm volatile("s_waitcnt vmcnt(6)" ::: "memory"); \
                       else                  asm volatile("s_waitcnt vmcnt(8)" ::: "memory"); } while (0)
#define FENCE_0() asm volatile("s_waitcnt vmcnt(0)" ::: "memory")
#define LGKM0()   asm volatile("s_waitcnt lgkmcnt(0)" ::: "memory")
#define BAR()     asm volatile("s_barrier" ::: "memory")

    stageB(0, 0);
    loadA(0, A0);
    for (int cc = 0; cc < NCH / 2; ++cc) {
        stageB(2 * cc + 1, 1);
        loadA(2 * cc + 1, A1);
        FENCE_N();
        BAR();
        compute(&Bs[0][0], A0);
        LGKM0();
        BAR();
        if (cc + 1 < NCH / 2) {
            stageB(2 * cc + 2, 0);
            loadA(2 * cc + 2, A0);
            FENCE_N();
        } else {
            FENCE_0();
        }
        BAR();
        compute(&Bs[1][0], A1);
        LGKM0();
        BAR();
    }
#undef FENCE_N
#undef FENCE_0
#undef LGKM0
#undef BAR

    float asv[8];
    if constexpr (FUSE_LS) {
        const int h = blockIdx.y;
#pragma unroll
        for (int t = 0; t < 8; t++) asv[t] = as_[h * 128 + t * 16 + mrow];
    }
    float lsp[4] = {0.f, 0.f, 0.f, 0.f};

#pragma unroll
    for (int t = 0; t < 8; t++) {
        int col = n0 + t * 16 + mrow;
        float sv = 0.f, sv2 = 0.f;
#pragma unroll
        for (int r = 0; r < 4; r++) {
            int orow = m0 + quad * 4 + r;
            if (orow < M) {
                float v = acc[t][r];
                if (RELU_BIAS) v = fmaxf(v + bias[col], 0.f);
                if (OUT_BF16)
                    ((u16*)outp)[(size_t)orow * NFULL + col] = f2bf(v);
                else
                    ((float*)outp)[(size_t)orow * NFULL + col] = v;
                if constexpr (FUSE_STATS) { sv += v; sv2 += v * v; }
                if constexpr (FUSE_LS) lsp[r] += v * asv[t];
            }
        }
        if constexpr (FUSE_STATS) {
            sv  += __shfl_xor(sv, 16, 64);  sv  += __shfl_xor(sv, 32, 64);
            sv2 += __shfl_xor(sv2, 16, 64); sv2 += __shfl_xor(sv2, 32, 64);
            if (quad == 0) {
                atomicAdd(&sstat[t * 16 + mrow], sv);
                atomicAdd(&sstat[128 + t * 16 + mrow], sv2);
            }
        }
    }
    if constexpr (FUSE_LS) {
        const int h = blockIdx.y;
#pragma unroll
        for (int r = 0; r < 4; r++) {
            float p = lsp[r];
            p += __shfl_xor(p, 1, 64); p += __shfl_xor(p, 2, 64);
            p += __shfl_xor(p, 4, 64); p += __shfl_xor(p, 8, 64);
            int orow = m0 + quad * 4 + r;
            if (mrow == 0 && orow < M) ls_out[orow * 4 + h] = p;
        }
    }
    if constexpr (FUSE_STATS) {
        __syncthreads();
        atomicAdd(&stats[threadIdx.x], sstat[threadIdx.x]);  // 256 threads
    }
}

// bn in place; optional bf16 fragment-major mirror; optional fused ld (dst attention dot)
__global__ void bn_apply(float* __restrict__ X, const float* __restrict__ stats,
                         const float* __restrict__ gamma, const float* __restrict__ beta,
                         u16* __restrict__ mirror, const float* __restrict__ weff,
                         float* __restrict__ ld_out, int M) {
    int i = blockIdx.x * 256 + threadIdx.x;   // M*16 threads, 8 cols each
    if (i >= M * 16) return;
    int row = i >> 4, cg = i & 15;
    float inv_m = 1.0f / (float)M;
    float4 lo = *reinterpret_cast<const float4*>(&X[(size_t)row * 128 + cg * 8]);
    float4 hi = *reinterpret_cast<const float4*>(&X[(size_t)row * 128 + cg * 8 + 4]);
    float v[8] = {lo.x, lo.y, lo.z, lo.w, hi.x, hi.y, hi.z, hi.w};
    u16 mb[8];
#pragma unroll
    for (int e = 0; e < 8; e++) {
        int col = cg * 8 + e;
        float mu = stats[col] * inv_m;
        float var = stats[128 + col] * inv_m - mu * mu;
        v[e] = gamma[col] * (v[e] - mu) * rsqrtf(var + BN_EPS) + beta[col];
        mb[e] = f2bf(v[e]);
    }
    *reinterpret_cast<float4*>(&X[(size_t)row * 128 + cg * 8]) = (float4){v[0], v[1], v[2], v[3]};
    *reinterpret_cast<float4*>(&X[(size_t)row * 128 + cg * 8 + 4]) = (float4){v[4], v[5], v[6], v[7]};
    if (mirror) {
        int kc = cg >> 2, quad = cg & 3, ml = quad * 16 + (row & 15), rt = row >> 4;
        *reinterpret_cast<uint4*>(&mirror[((size_t)(rt * 4 + kc) * 64 + ml) * 8]) =
            *reinterpret_cast<const uint4*>(mb);
    }
    if (ld_out) {
#pragma unroll
        for (int h = 0; h < 4; h++) {
            float p = 0.f;
#pragma unroll
            for (int e = 0; e < 8; e++) p += v[e] * weff[h * 128 + cg * 8 + e];
            p += __shfl_xor(p, 1, 64); p += __shfl_xor(p, 2, 64);
            p += __shfl_xor(p, 4, 64); p += __shfl_xor(p, 8, 64);
            if (cg == 0) ld_out[row * 4 + h] = p;
        }
    }
}

// ---------------- CSR build (both relations) ----------------
__global__ void count_both(const int* __restrict__ e1s, const int* __restrict__ e1d,
                           const int* __restrict__ e2s, const int* __restrict__ e2d,
                           int* __restrict__ deg1, int* __restrict__ deg2) {
    int i = blockIdx.x * 256 + threadIdx.x;
    if (i < E_EDGES + N_DIS) {
        int d;
        if (i < E_EDGES) { int s = e1s[i]; d = e1d[i]; if (s == d) return; }
        else d = i - E_EDGES;
        atomicAdd(&deg1[d], 1);
        return;
    }
    i -= E_EDGES + N_DIS;
    if (i < E_EDGES + N_GENE) {
        int d;
        if (i < E_EDGES) { int s = e2s[i]; d = e2d[i]; if (s == d) return; }
        else d = i - E_EDGES;
        atomicAdd(&deg2[d], 1);
    }
}

// 3-phase scan, both relations in one grid (blocks [0,NB) rel1, [NB,2NB) rel2)
__global__ void block_sum_both(const int* __restrict__ deg1, const int* __restrict__ deg2,
                               int* __restrict__ bsum, int nb) {
    __shared__ int sh[256];
    int rel = blockIdx.x >= nb;
    int blk = rel ? blockIdx.x - nb : blockIdx.x;
    const int* deg = rel ? deg2 : deg1;
    int i = blk * 256 + threadIdx.x;
    sh[threadIdx.x] = (i < N_GENE) ? deg[i] : 0;
    __syncthreads();
    for (int s = 128; s > 0; s >>= 1) {
        if (threadIdx.x < s) sh[threadIdx.x] += sh[threadIdx.x + s];
        __syncthreads();
    }
    if (threadIdx.x == 0) bsum[blockIdx.x] = sh[0];
}

__global__ void scan_bsum_both(int* __restrict__ bsum, int nb,
                               int* __restrict__ offs1, int* __restrict__ offs2) {
    __shared__ int sh[256];
    int* bs = bsum + blockIdx.x * nb;
    int tid = threadIdx.x;
    int v = (tid < nb) ? bs[tid] : 0;
    sh[tid] = v;
    __syncthreads();
    for (int off = 1; off < 256; off <<= 1) {
        int t = (tid >= off) ? sh[tid - off] : 0;
        __syncthreads();
        sh[tid] += t;
        __syncthreads();
    }
    if (tid < nb) bs[tid] = sh[tid] - v;   // exclusive
    if (tid == 255) (blockIdx.x ? offs2 : offs1)[N_GENE] = sh[255];
}

__global__ void scan_final_both(const int* __restrict__ deg1, const int* __restrict__ deg2,
                                const int* __restrict__ bsum, int nb,
                                int* __restrict__ offs1, int* __restrict__ cur1,
                                int* __restrict__ offs2, int* __restrict__ cur2) {
    __shared__ int sh[256];
    int rel = blockIdx.x >= nb;
    int blk = rel ? blockIdx.x - nb : blockIdx.x;
    const int* deg = rel ? deg2 : deg1;
    int* offs = rel ? offs2 : offs1;
    int* cur  = rel ? cur2  : cur1;
    int i = blk * 256 + threadIdx.x, tid = threadIdx.x;
    int v = (i < N_GENE) ? deg[i] : 0;
    sh[tid] = v;
    __syncthreads();
    for (int off = 1; off < 256; off <<= 1) {
        int t = (tid >= off) ? sh[tid - off] : 0;
        __syncthreads();
        sh[tid] += t;
        __syncthreads();
    }
    int ex = bsum[blockIdx.x] + sh[tid] - v;
    if (i < N_GENE) { offs[i] = ex; cur[i] = ex; }
}

__global__ void scatter_both(const int* __restrict__ e1s, const int* __restrict__ e1d,
                             const int* __restrict__ e2s, const int* __restrict__ e2d,
                             int* __restrict__ cur1, int* __restrict__ cur2,
                             int* __restrict__ esrc1, int* __restrict__ esrc2) {
    int i = blockIdx.x * 256 + threadIdx.x;
    if (i < E_EDGES + N_DIS) {
        int s, d;
        if (i < E_EDGES) { s = e1s[i]; d = e1d[i]; if (s == d) return; }
        else { s = i - E_EDGES; d = s; }
        esrc1[atomicAdd(&cur1[d], 1)] = s;
        return;
    }
    i -= E_EDGES + N_DIS;
    if (i < E_EDGES + N_GENE) {
        int s, d;
        if (i < E_EDGES) { s = e2s[i]; d = e2d[i]; if (s == d) return; }
        else { s = i - E_EDGES; d = s; }
        esrc2[atomicAdd(&cur2[d], 1)] = s;
    }
}

// ---- GAT aggregation: one wave per dst node; updates xdst_out in place ----
// optional fused: ld for NEXT relation (from updated row), bf16 fragment-major mirror
__global__ void gat_kernel(const int* __restrict__ offs, const int* __restrict__ esrc,
                           const float* __restrict__ ls, const float* __restrict__ ld,
                           const u16* __restrict__ xs, const float* __restrict__ bias,
                           float* __restrict__ xdst_out, u16* __restrict__ mirror,
                           const float* __restrict__ weff2, float* __restrict__ ld2_out,
                           int n_dst) {
    int wid = (blockIdx.x * blockDim.x + threadIdx.x) >> 6;
    int lane = threadIdx.x & 63;
    if (wid >= n_dst) return;
    int h = lane >> 4;
    int beg = offs[wid], end = offs[wid + 1];
    float ldv = ld[wid * 4 + h];
    float m = -INFINITY;
    for (int j = beg; j < end; j++) {
        int s = esrc[j];
        float l = ls[s * 4 + h] + ldv;
        l = l > 0.f ? l : 0.2f * l;
        m = fmaxf(m, l);
    }
    float denom = 0.f;
    float acc[8] = {0.f, 0.f, 0.f, 0.f, 0.f, 0.f, 0.f, 0.f};
    for (int j = beg; j < end; j++) {
        int s = esrc[j];
        float l = ls[s * 4 + h] + ldv;
        l = l > 0.f ? l : 0.2f * l;
        float p = __expf(l - m);
        denom += p;
        float xv[8];
        load_bf16x8(xs + (size_t)s * 512 + lane * 8, xv);
        #pragma unroll
        for (int k = 0; k < 8; k++) acc[k] += p * xv[k];
    }
    float dinv = denom > 0.f ? 1.f / denom : 1.f;
    #pragma unroll
    for (int k = 0; k < 8; k++) {
        float v = acc[k] * dinv;
        v += __shfl_xor(v, 16, 64);
        v += __shfl_xor(v, 32, 64);
        acc[k] = v * 0.25f;
    }
    if (lane < 16) {
        int c0 = lane * 8;
        float vout[8];
        #pragma unroll
        for (int k = 0; k < 8; k++) {
            vout[k] = xdst_out[(size_t)wid * 128 + c0 + k] + acc[k] + bias[c0 + k];
            xdst_out[(size_t)wid * 128 + c0 + k] = vout[k];
        }
        if (mirror) {
            unsigned pk[4];
            #pragma unroll
            for (int kk = 0; kk < 4; kk++)
                pk[kk] = (unsigned)f2bf(vout[2 * kk]) | ((unsigned)f2bf(vout[2 * kk + 1]) << 16);
            int kc = lane >> 2, quad = lane & 3, ml = quad * 16 + (wid & 15), rt = wid >> 4;
            *reinterpret_cast<uint4*>(&mirror[((size_t)(rt * 4 + kc) * 64 + ml) * 8]) =
                *reinterpret_cast<const uint4*>(pk);
        }
        if (weff2) {
            #pragma unroll
            for (int hh = 0; hh < 4; hh++) {
                float p = 0.f;
                #pragma unroll
                for (int k = 0; k < 8; k++) p += vout[k] * weff2[hh * 128 + c0 + k];
                p += __shfl_xor(p, 1, 64); p += __shfl_xor(p, 2, 64);
                p += __shfl_xor(p, 4, 64); p += __shfl_xor(p, 8, 64);
                if (lane == 0) ld2_out[wid * 4 + hh] = p;
            }
        }
    }
}

static inline int cdiv(int a, int b) { return (a + b - 1) / b; }

extern "C" void kernel_launch(void* const* d_in, const int* in_sizes, int n_in,
                              void* d_out, int out_size, void* d_ws, size_t ws_size,
                              hipStream_t stream) {
    const float* x_gene = (const float*)d_in[0];
    const float* x_dis  = (const float*)d_in[1];
    const int* e1s = (const int*)d_in[2];
    const int* e1d = (const int*)d_in[3];
    const int* e2s = (const int*)d_in[4];
    const int* e2d = (const int*)d_in[5];
    const float *Wg = (const float*)d_in[6],  *bg = (const float*)d_in[7];
    const float *gg = (const float*)d_in[8],  *betag = (const float*)d_in[9];
    const float *Wd = (const float*)d_in[10], *bd = (const float*)d_in[11];
    const float *gd = (const float*)d_in[12], *betad = (const float*)d_in[13];
    const float *W1s = (const float*)d_in[14], *W1d = (const float*)d_in[15];
    const float *a1s = (const float*)d_in[16], *a1d = (const float*)d_in[17];
    const float *b1  = (const float*)d_in[18];
    const float *W2s = (const float*)d_in[19], *W2d = (const float*)d_in[20];
    const float *a2s = (const float*)d_in[21], *a2d = (const float*)d_in[22];
    const float *b2  = (const float*)d_in[23];

    float* gene_f = (float*)d_out;                         // [N_GENE,128]
    float* dis_f  = (float*)d_out + (size_t)N_GENE * 128;  // [N_DIS,128]

    char* p = (char*)d_ws;
    auto alloc = [&](size_t bytes) {
        char* r = p;
        p += (bytes + 255) & ~(size_t)255;
        return r;
    };
    u16*   xs_buf  = (u16*)  alloc((size_t)N_GENE * 512 * 2);
    u16*   gene_bf = (u16*)  alloc((size_t)cdiv(N_GENE, 16) * 2048 * 2);
    u16*   dis_bf  = (u16*)  alloc((size_t)cdiv(N_DIS, 16) * 2048 * 2);
    float* ls_buf  = (float*)alloc((size_t)N_GENE * 4 * 4);
    float* ld1_buf = (float*)alloc((size_t)N_GENE * 4 * 4);
    float* ld2_buf = (float*)alloc((size_t)N_GENE * 4 * 4);
    float* weff    = (float*)alloc(1024 * 4);              // [rel1:512 | rel2:512]
    float* stats_g = (float*)alloc(256 * 4);
    float* stats_d = (float*)alloc(256 * 4);
    int*   deg1    = (int*)  alloc((size_t)N_GENE * 4);
    int*   deg2    = (int*)  alloc((size_t)N_GENE * 4);
    int*   offs1   = (int*)  alloc((size_t)(N_GENE + 1) * 4);
    int*   offs2   = (int*)  alloc((size_t)(N_GENE + 1) * 4);
    int*   cur1    = (int*)  alloc((size_t)N_GENE * 4);
    int*   cur2    = (int*)  alloc((size_t)N_GENE * 4);
    int*   bsum    = (int*)  alloc(512 * 4);
    int*   esrc1   = (int*)  alloc((size_t)(E_EDGES + N_GENE) * 4);
    int*   esrc2   = (int*)  alloc((size_t)(E_EDGES + N_GENE) * 4);
    u16*   Wgt  = (u16*)alloc((size_t)8 * 16 * 512 * 2);   // [8nt][16kc][512]
    u16*   Wdt  = (u16*)alloc((size_t)8 * 8 * 512 * 2);    // [8nt][8kc][512]
    u16*   W1st = (u16*)alloc((size_t)32 * 4 * 512 * 2);   // [32nt][4kc][512]
    u16*   W2st = (u16*)alloc((size_t)32 * 4 * 512 * 2);

    const int NB = cdiv(N_GENE, 256);  // 196

    // ---- front: packs + zeros + weff (1 kernel), then CSR for both relations ----
    const int PREP_T = 8192 + 4096 + 8192 + 8192 + 256 + 256 + N_GENE + N_GENE + 1024;
    prep<<<cdiv(PREP_T, 256), 256, 0, stream>>>(Wg, Wd, W1s, W2s, Wgt, Wdt, W1st, W2st,
                                                stats_g, stats_d, deg1, deg2,
                                                W1d, a1d, W2d, a2d, weff);
    const int EB = cdiv((E_EDGES + N_DIS) + (E_EDGES + N_GENE), 256);
    count_both<<<EB, 256, 0, stream>>>(e1s, e1d, e2s, e2d, deg1, deg2);
    block_sum_both<<<2 * NB, 256, 0, stream>>>(deg1, deg2, bsum, NB);
    scan_bsum_both<<<2, 256, 0, stream>>>(bsum, NB, offs1, offs2);
    scan_final_both<<<2 * NB, 256, 0, stream>>>(deg1, deg2, bsum, NB, offs1, cur1, offs2, cur2);
    scatter_both<<<EB, 256, 0, stream>>>(e1s, e1d, e2s, e2d, cur1, cur2, esrc1, esrc2);

    // ---- encode gene (stats fused into GEMM; ld1 fused into bn) ----
    gemm_lds<512, false, true, false, true, false><<<dim3(cdiv(N_GENE, 64), 1), 256, 0, stream>>>(
        x_gene, Wgt, bg, gene_f, N_GENE, 128, stats_g, nullptr, nullptr);
    bn_apply<<<cdiv(N_GENE * 16, 256), 256, 0, stream>>>(gene_f, stats_g, gg, betag,
                                                         nullptr, weff, ld1_buf, N_GENE);

    // ---- encode dis ----
    gemm_lds<256, false, true, false, true, false><<<dim3(cdiv(N_DIS, 64), 1), 256, 0, stream>>>(
        x_dis, Wdt, bd, dis_f, N_DIS, 128, stats_d, nullptr, nullptr);
    bn_apply<<<cdiv(N_DIS * 16, 256), 256, 0, stream>>>(dis_f, stats_d, gd, betad,
                                                        dis_bf, nullptr, nullptr, N_DIS);

    // ---- relation 1: Disease -> Gene (ls fused into GEMM; ld2 fused into gat) ----
    gemm_lds<128, true, false, true, false, true><<<dim3(cdiv(N_DIS, 64), 4), 256, 0, stream>>>(
        dis_bf, W1st, nullptr, xs_buf, N_DIS, 512, nullptr, a1s, ls_buf);
    gat_kernel<<<cdiv(N_GENE, 4), 256, 0, stream>>>(offs1, esrc1, ls_buf, ld1_buf, xs_buf, b1,
                                                    gene_f, gene_bf, weff + 512, ld2_buf, N_GENE);

    // ---- relation 2: Gene -> Gene ----
    gemm_lds<128, true, false, true, false, true><<<dim3(cdiv(N_GENE, 64), 4), 256, 0, stream>>>(
        gene_bf, W2st, nullptr, xs_buf, N_GENE, 512, nullptr, a2s, ls_buf);
    gat_kernel<<<cdiv(N_GENE, 4), 256, 0, stream>>>(offs2, esrc2, ls_buf, ld2_buf, xs_buf, b2,
                                                    gene_f, nullptr, nullptr, nullptr, N_GENE);
}